// Round 6
// baseline (394.105 us; speedup 1.0000x reference)
//
#include <hip/hip_runtime.h>
#include <hip/hip_cooperative_groups.h>

namespace cg = cooperative_groups;

#define N_SPIKES 16384
#define N_UNITS  256
#define N_NEIGHB 128
#define RANK     5
#define NC       64
#define NC_OBS   12
#define N_CAND   10
#define DD       60                 // RANK * NC_OBS
#define DD4      15                 // DD / 4
#define OUT_COLS 61
#define OUT_SIZE (N_UNITS * OUT_COLS)   // 15616
#define NSB      8                  // sub-bins per unit (counter de-contention)
#define SCAP     192                // per-sub-bin capacity (mean 80, sd 8.9)
#define CNT_PAD  4                  // 16B per counter
#define CAP      (NSB * SCAP)       // 1536: S2 staging can hold worst case

// ---------------------------------------------------------------------------
// Fused cooperative kernel: P -> grid.sync -> S1 -> grid.sync -> S2.
// R5 theory: all three sub-kernels are individually <40us (invisible under
// the harness's 41us ws-poison fills in top-5); bottom-up estimates leave
// ~25-40us of the 71us non-poison budget unexplained => inter-dispatch
// launch/drain gaps.  One cooperative launch removes 2 of 3 launches and
// both gaps, and makes OUR time finally visible as a single dispatch.
// 256 blocks x 1024 thr: co-resident by construction (1 block/CU), 33KB LDS.
// Phase logic is IDENTICAL to the R5 three-kernel version (P uses waves 0-7,
// waves 8-15 idle through it; S2 accumulates with 64 groups instead of 32).
// __threadfence + grid.sync gives cross-XCD visibility of w_buf/bins.
// ---------------------------------------------------------------------------
struct SmemP  { float nu[128 * 61]; float q2[128 * 4]; };
struct SmemS2 { int2 rec[CAP]; float red[16][OUT_COLS]; int cnts[NSB]; int offs[NSB + 1]; };

__global__ __launch_bounds__(1024) void fused_kernel(
    const float* __restrict__ features, const float* __restrict__ mu,
    const float* __restrict__ Coo_inv, const int* __restrict__ obs_ix,
    const float* __restrict__ log_prop, const float* __restrict__ noise_lp,
    const int* __restrict__ cands, const int* __restrict__ nid,
    float* __restrict__ w_buf, float* __restrict__ b_buf,
    int* __restrict__ gcount, int2* __restrict__ bins,
    float* __restrict__ out)
{
    __shared__ __align__(16) char smem_raw[sizeof(SmemP) > sizeof(SmemS2) ?
                                           sizeof(SmemP) : sizeof(SmemS2)];
    cg::grid_group grid = cg::this_grid();

    const int b    = blockIdx.x;
    const int tid  = threadIdx.x;
    const int lane = tid & 63;
    const int wave = tid >> 6;          // 0..15

    // ================= Phase P: precompute w, b (waves 0..7) =================
    {
        SmemP* sm = reinterpret_cast<SmemP*>(smem_raw);
        const int h  = b >> 1;
        const int ub = (b & 1) * 128;

        if (tid < 32) gcount[b * 32 + tid] = 0;   // 256*32 = all 8192 counters

        if (tid < 512) {                // gather nu for 128 units into LDS
            const int ut  = tid >> 2;
            const int dqt = tid & 3;
            const float* __restrict__ mub = mu + (ub + ut) * (RANK * NC);
#pragma unroll
            for (int j = 0; j < DD4; ++j) {
                const int d  = dqt * DD4 + j;
                const int r  = d / NC_OBS;
                const int jj = d - r * NC_OBS;
                const int ch = obs_ix[h * NC_OBS + jj];
                sm->nu[ut * 61 + d] = mub[r * NC + ch];
            }
        }
        __syncthreads();

        const int ug    = wave >> 2;                                  // 0/1
        const int dq    = __builtin_amdgcn_readfirstlane(wave & 3);
        const int u_loc = ug * 64 + lane;
        const int u     = ub + u_loc;
        const int p     = h * N_UNITS + u;

        if (wave < 8) {
            const float* __restrict__ Crow_base = Coo_inv + h * DD * DD + dq * DD4;
            float wreg[DD4];
#pragma unroll
            for (int j = 0; j < DD4; ++j) wreg[j] = 0.f;

            for (int e = 0; e < DD; ++e) {
                const float nu_e = sm->nu[u_loc * 61 + e];
                const float* __restrict__ Crow = Crow_base + e * DD;
#pragma unroll
                for (int j = 0; j < DD4; ++j)
                    wreg[j] = fmaf(Crow[j], nu_e, wreg[j]);
            }

            float q2 = 0.f;
#pragma unroll
            for (int j = 0; j < DD4; ++j)
                q2 += wreg[j] * sm->nu[u_loc * 61 + dq * DD4 + j];
            sm->q2[u_loc * 4 + dq] = q2;

            float* __restrict__ wp = w_buf + p * DD + dq * DD4;
#pragma unroll
            for (int j = 0; j < DD4; ++j) wp[j] = wreg[j];
        }
        __syncthreads();
        if (wave < 8 && (wave & 3) == 0) {
            const float q2s = sm->q2[u_loc * 4 + 0] + sm->q2[u_loc * 4 + 1]
                            + sm->q2[u_loc * 4 + 2] + sm->q2[u_loc * 4 + 3];
            b_buf[p] = log_prop[u] - 0.5f * q2s;
        }
    }

    __threadfence();
    grid.sync();

    // ================= Phase S1: q-compute + bin (all 16 waves) ==============
    {
        const int c    = lane & 15;         // candidate slot (0..9 active)
        const int s    = lane >> 4;         // spike slot within wave
        const int n    = b * 64 + wave * 4 + s;
        const int sb   = b & (NSB - 1);
        const bool act = (c < N_CAND);
        const int cc   = act ? c : (N_CAND - 1);

        const float4* __restrict__ f4 = (const float4*)features;
        const float4* __restrict__ w4 = (const float4*)w_buf;

        const int   h   = nid[n];
        const float nlp = noise_lp[0];
        const int   uc  = cands[n * N_CAND + cc];
        const int   p   = h * N_UNITS + uc;
        const float bb  = b_buf[p];

        float t = 0.f;
#pragma unroll
        for (int k = 0; k < DD4; ++k) {
            const float4 wv = w4[p * DD4 + k];
            const float4 xv = f4[n * DD4 + k];   // same addr across group: L1 bcast
            t += wv.x * xv.x + wv.y * xv.y + wv.z * xv.z + wv.w * xv.w;
        }
        float ll = act ? (bb + t) : -3.4e38f;

        float m = ll;
        m = fmaxf(m, __shfl_xor(m, 1, 16));
        m = fmaxf(m, __shfl_xor(m, 2, 16));
        m = fmaxf(m, __shfl_xor(m, 4, 16));
        m = fmaxf(m, __shfl_xor(m, 8, 16));
        m = fmaxf(m, nlp);
        const float e = act ? __expf(ll - m) : 0.f;
        float ssum = e;
        ssum += __shfl_xor(ssum, 1, 16);
        ssum += __shfl_xor(ssum, 2, 16);
        ssum += __shfl_xor(ssum, 4, 16);
        ssum += __shfl_xor(ssum, 8, 16);
        ssum += __expf(nlp - m);
        const float q = e / ssum;

        if (act && q > 0.f) {
            const int bi  = uc * NSB + sb;
            const int pos = atomicAdd(&gcount[bi * CNT_PAD], 1);
            if (pos < SCAP) bins[bi * SCAP + pos] = make_int2(n, __float_as_int(q));
        }
    }

    __threadfence();
    grid.sync();

    // ================= Phase S2: per-unit gather-accumulate ==================
    {
        SmemS2* sm = reinterpret_cast<SmemS2*>(smem_raw);
        const int u = b;

        if (tid < NSB) {
            int c = gcount[(u * NSB + tid) * CNT_PAD];
            sm->cnts[tid] = c < SCAP ? c : SCAP;
        }
        __syncthreads();
        if (tid == 0) {
            int o = 0;
#pragma unroll
            for (int sb = 0; sb < NSB; ++sb) { sm->offs[sb] = o; o += sm->cnts[sb]; }
            sm->offs[NSB] = o;
        }
        __syncthreads();

        if (wave < NSB) {   // wave-parallel staging: wave w copies sub-bin w
            const int base = sm->offs[wave];
            const int cnt  = sm->cnts[wave];
            const int2* __restrict__ src = bins + (u * NSB + wave) * SCAP;
            for (int i = lane; i < cnt; i += 64) sm->rec[base + i] = src[i];
        }
        __syncthreads();

        const int total = sm->offs[NSB];
        const int g = tid >> 4;             // group 0..63
        const int l = lane & 15;

        const float4* __restrict__ f4 = (const float4*)features;
        float4 a = {0.f, 0.f, 0.f, 0.f};
        float sq = 0.f;

        for (int i = g; i < total; i += 64) {
            const int2 r = sm->rec[i];               // LDS broadcast within group
            const float q = __int_as_float(r.y);
            if (l < DD4) {
                const float4 xv = f4[r.x * DD4 + l]; // 15 lanes: 240B contiguous
                a.x = fmaf(q, xv.x, a.x);
                a.y = fmaf(q, xv.y, a.y);
                a.z = fmaf(q, xv.z, a.z);
                a.w = fmaf(q, xv.w, a.w);
            } else if (l == DD4) {
                sq += q;
            }
        }

        // reduce across the 4 groups within each wave
        a.x += __shfl_xor(a.x, 16, 64);  a.x += __shfl_xor(a.x, 32, 64);
        a.y += __shfl_xor(a.y, 16, 64);  a.y += __shfl_xor(a.y, 32, 64);
        a.z += __shfl_xor(a.z, 16, 64);  a.z += __shfl_xor(a.z, 32, 64);
        a.w += __shfl_xor(a.w, 16, 64);  a.w += __shfl_xor(a.w, 32, 64);
        sq  += __shfl_xor(sq, 16, 64);   sq  += __shfl_xor(sq, 32, 64);

        if (lane < DD4) {
            sm->red[wave][1 + 4*lane + 0] = a.x;
            sm->red[wave][1 + 4*lane + 1] = a.y;
            sm->red[wave][1 + 4*lane + 2] = a.z;
            sm->red[wave][1 + 4*lane + 3] = a.w;
        } else if (lane == DD4) {
            sm->red[wave][0] = sq;
        }
        __syncthreads();

        if (tid < OUT_COLS) {
            float ssum = 0.f;
#pragma unroll
            for (int w = 0; w < 16; ++w) ssum += sm->red[w][tid];
            out[u * OUT_COLS + tid] = ssum;
        }
    }
}

// ---------------------------------------------------------------------------
// Fallback path (identical logic, 3 dispatches) if cooperative launch fails.
// ---------------------------------------------------------------------------
__global__ __launch_bounds__(512) void precompute_kernel(
    const float* __restrict__ mu, const float* __restrict__ Coo_inv,
    const int* __restrict__ obs_ix, const float* __restrict__ log_prop,
    float* __restrict__ w_buf, float* __restrict__ b_buf,
    int* __restrict__ gcount)
{
    __shared__ float nu_lds[128 * 61];
    __shared__ float q2_lds[128 * 4];

    const int b   = blockIdx.x;
    const int h   = b >> 1;
    const int ub  = (b & 1) * 128;
    const int tid = threadIdx.x;

    if (tid < 32) gcount[b * 32 + tid] = 0;

    {
        const int ut  = tid >> 2;
        const int dqt = tid & 3;
        const float* __restrict__ mub = mu + (ub + ut) * (RANK * NC);
#pragma unroll
        for (int j = 0; j < DD4; ++j) {
            const int d = dqt * DD4 + j;
            const int r = d / NC_OBS;
            const int jj = d - r * NC_OBS;
            const int ch = obs_ix[h * NC_OBS + jj];
            nu_lds[ut * 61 + d] = mub[r * NC + ch];
        }
    }
    __syncthreads();

    const int lane  = tid & 63;
    const int wave  = tid >> 6;
    const int ug    = wave >> 2;
    const int dq    = __builtin_amdgcn_readfirstlane(wave & 3);
    const int u_loc = ug * 64 + lane;
    const int u     = ub + u_loc;
    const int p     = h * N_UNITS + u;

    const float* __restrict__ Crow_base = Coo_inv + h * DD * DD + dq * DD4;

    float wreg[DD4];
#pragma unroll
    for (int j = 0; j < DD4; ++j) wreg[j] = 0.f;

    for (int e = 0; e < DD; ++e) {
        const float nu_e = nu_lds[u_loc * 61 + e];
        const float* __restrict__ Crow = Crow_base + e * DD;
#pragma unroll
        for (int j = 0; j < DD4; ++j)
            wreg[j] = fmaf(Crow[j], nu_e, wreg[j]);
    }

    float q2 = 0.f;
#pragma unroll
    for (int j = 0; j < DD4; ++j) q2 += wreg[j] * nu_lds[u_loc * 61 + dq * DD4 + j];
    q2_lds[u_loc * 4 + dq] = q2;

    float* __restrict__ wp = w_buf + p * DD + dq * DD4;
#pragma unroll
    for (int j = 0; j < DD4; ++j) wp[j] = wreg[j];

    __syncthreads();
    if ((wave & 3) == 0) {
        const float q2s = q2_lds[u_loc * 4 + 0] + q2_lds[u_loc * 4 + 1]
                        + q2_lds[u_loc * 4 + 2] + q2_lds[u_loc * 4 + 3];
        b_buf[p] = log_prop[u] - 0.5f * q2s;
    }
}

__global__ __launch_bounds__(1024) void spike_bin_kernel(
    const float* __restrict__ features, const float* __restrict__ noise_lp,
    const int* __restrict__ cands, const int* __restrict__ nid,
    const float* __restrict__ w_buf, const float* __restrict__ b_buf,
    int* __restrict__ gcount, int2* __restrict__ bins)
{
    const int tid  = threadIdx.x;
    const int lane = tid & 63;
    const int wave = tid >> 6;
    const int c    = lane & 15;
    const int s    = lane >> 4;
    const int n    = blockIdx.x * 64 + wave * 4 + s;
    const int sb   = blockIdx.x & (NSB - 1);
    const bool act = (c < N_CAND);
    const int cc   = act ? c : (N_CAND - 1);

    const float4* __restrict__ f4 = (const float4*)features;
    const float4* __restrict__ w4 = (const float4*)w_buf;

    const int   h   = nid[n];
    const float nlp = noise_lp[0];
    const int   uc  = cands[n * N_CAND + cc];
    const int   p   = h * N_UNITS + uc;
    const float bb  = b_buf[p];

    float t = 0.f;
#pragma unroll
    for (int k = 0; k < DD4; ++k) {
        const float4 wv = w4[p * DD4 + k];
        const float4 xv = f4[n * DD4 + k];
        t += wv.x * xv.x + wv.y * xv.y + wv.z * xv.z + wv.w * xv.w;
    }
    float ll = act ? (bb + t) : -3.4e38f;

    float m = ll;
    m = fmaxf(m, __shfl_xor(m, 1, 16));
    m = fmaxf(m, __shfl_xor(m, 2, 16));
    m = fmaxf(m, __shfl_xor(m, 4, 16));
    m = fmaxf(m, __shfl_xor(m, 8, 16));
    m = fmaxf(m, nlp);
    const float e = act ? __expf(ll - m) : 0.f;
    float ssum = e;
    ssum += __shfl_xor(ssum, 1, 16);
    ssum += __shfl_xor(ssum, 2, 16);
    ssum += __shfl_xor(ssum, 4, 16);
    ssum += __shfl_xor(ssum, 8, 16);
    ssum += __expf(nlp - m);
    const float q = e / ssum;

    if (act && q > 0.f) {
        const int bi  = uc * NSB + sb;
        const int pos = atomicAdd(&gcount[bi * CNT_PAD], 1);
        if (pos < SCAP) bins[bi * SCAP + pos] = make_int2(n, __float_as_int(q));
    }
}

__global__ __launch_bounds__(512) void unit_accum_kernel(
    const float* __restrict__ features, const int* __restrict__ gcount,
    const int2* __restrict__ bins, float* __restrict__ out)
{
    __shared__ int2  rec[CAP];
    __shared__ float red[8][OUT_COLS];
    __shared__ int   cnts[NSB];
    __shared__ int   offs[NSB + 1];

    const int u    = blockIdx.x;
    const int tid  = threadIdx.x;
    const int lane = tid & 63;
    const int wave = tid >> 6;

    if (tid < NSB) {
        int c = gcount[(u * NSB + tid) * CNT_PAD];
        cnts[tid] = c < SCAP ? c : SCAP;
    }
    __syncthreads();
    if (tid == 0) {
        int o = 0;
#pragma unroll
        for (int sb = 0; sb < NSB; ++sb) { offs[sb] = o; o += cnts[sb]; }
        offs[NSB] = o;
    }
    __syncthreads();

    {
        const int base = offs[wave];
        const int cnt  = cnts[wave];
        const int2* __restrict__ src = bins + (u * NSB + wave) * SCAP;
        for (int i = lane; i < cnt; i += 64) rec[base + i] = src[i];
    }
    __syncthreads();

    const int total = offs[NSB];
    const int g = tid >> 4;
    const int l = lane & 15;

    const float4* __restrict__ f4 = (const float4*)features;
    float4 a = {0.f, 0.f, 0.f, 0.f};
    float sq = 0.f;

    for (int i = g; i < total; i += 32) {
        const int2 r = rec[i];
        const float q = __int_as_float(r.y);
        if (l < DD4) {
            const float4 xv = f4[r.x * DD4 + l];
            a.x = fmaf(q, xv.x, a.x);
            a.y = fmaf(q, xv.y, a.y);
            a.z = fmaf(q, xv.z, a.z);
            a.w = fmaf(q, xv.w, a.w);
        } else if (l == DD4) {
            sq += q;
        }
    }

    a.x += __shfl_xor(a.x, 16, 64);  a.x += __shfl_xor(a.x, 32, 64);
    a.y += __shfl_xor(a.y, 16, 64);  a.y += __shfl_xor(a.y, 32, 64);
    a.z += __shfl_xor(a.z, 16, 64);  a.z += __shfl_xor(a.z, 32, 64);
    a.w += __shfl_xor(a.w, 16, 64);  a.w += __shfl_xor(a.w, 32, 64);
    sq  += __shfl_xor(sq, 16, 64);   sq  += __shfl_xor(sq, 32, 64);

    if (lane < DD4) {
        red[wave][1 + 4*lane + 0] = a.x;
        red[wave][1 + 4*lane + 1] = a.y;
        red[wave][1 + 4*lane + 2] = a.z;
        red[wave][1 + 4*lane + 3] = a.w;
    } else if (lane == DD4) {
        red[wave][0] = sq;
    }
    __syncthreads();

    if (tid < OUT_COLS) {
        float ssum = 0.f;
#pragma unroll
        for (int w = 0; w < 8; ++w) ssum += red[w][tid];
        out[u * OUT_COLS + tid] = ssum;
    }
}

extern "C" void kernel_launch(void* const* d_in, const int* in_sizes, int n_in,
                              void* d_out, int out_size, void* d_ws, size_t ws_size,
                              hipStream_t stream) {
    const float* features    = (const float*)d_in[0];
    const float* mu          = (const float*)d_in[1];
    const float* Coo_inv     = (const float*)d_in[2];
    // d_in[3] = Coo_logdet : unused (cancels in softmax)
    const float* log_prop    = (const float*)d_in[4];
    const float* noise_lp    = (const float*)d_in[5];
    const int*   cands       = (const int*)d_in[6];
    const int*   nid         = (const int*)d_in[7];
    const int*   obs_ix      = (const int*)d_in[8];
    float* out = (float*)d_out;

    char* ws = (char*)d_ws;
    float* w_buf  = (float*)ws;                   // 128*256*60*4 = 7,864,320 B
    float* b_buf  = (float*)(ws + 7864320);       // 128*256*4    =   131,072 B
    int*   gcount = (int*)(ws + 7995392);         // 256*8*4*4    =    32,768 B
    int2*  bins   = (int2*)(ws + 8028160);        // 256*8*192*8  = 3,145,728 B

    void* args[] = {
        (void*)&features, (void*)&mu, (void*)&Coo_inv, (void*)&obs_ix,
        (void*)&log_prop, (void*)&noise_lp, (void*)&cands, (void*)&nid,
        (void*)&w_buf, (void*)&b_buf, (void*)&gcount, (void*)&bins, (void*)&out
    };
    hipError_t err = hipLaunchCooperativeKernel(
        (const void*)fused_kernel, dim3(256), dim3(1024), args, 0, stream);

    if (err != hipSuccess) {
        // fallback: three stream-ordered dispatches (identical logic)
        precompute_kernel<<<256, 512, 0, stream>>>(mu, Coo_inv, obs_ix, log_prop,
                                                   w_buf, b_buf, gcount);
        spike_bin_kernel<<<256, 1024, 0, stream>>>(features, noise_lp, cands, nid,
                                                   w_buf, b_buf, gcount, bins);
        unit_accum_kernel<<<256, 512, 0, stream>>>(features, gcount, bins, out);
    }
}

// Round 7
// 111.026 us; speedup vs baseline: 3.5497x; 3.5497x over previous
//
#include <hip/hip_runtime.h>

#define N_SPIKES 16384
#define N_UNITS  256
#define N_NEIGHB 128
#define RANK     5
#define NC       64
#define NC_OBS   12
#define N_CAND   10
#define DD       60                 // RANK * NC_OBS
#define DD4      15                 // DD / 4
#define OUT_COLS 61
#define OUT_SIZE (N_UNITS * OUT_COLS)   // 15616
#define NSB      8                  // sub-bins per unit (counter de-contention)
#define SCAP     192                // per-sub-bin capacity (mean 80, sd 8.9)
#define CNT_PAD  4                  // 16B per counter
#define CAP      (NSB * SCAP)       // 1536: S2 staging holds worst case

// ---------------------------------------------------------------------------
// Kernel P v3: LDS-staged Cinv.  R6 post-mortem budget puts P at ~35-45us;
// mechanism: v2's inner loop reads Coo_inv rows via wave-uniform s_loads --
// a 60-deep dependent s_load->waitcnt->FMA chain at 2 waves/SIMD, ~300cyc
// L2 latency each, nothing to hide it.  v3 stages the full 14.4KB Cinv[h]
// into LDS ONCE per block (coalesced float4), inner loop reads the 15-wide
// slice from LDS (wave-uniform addr -> broadcast, conflict-free, ds_read
// pipelines under lgkmcnt).  Grid/block/output layout identical to v2.
// Also zeroes gcount (replaces the memset dispatch).
// ---------------------------------------------------------------------------
__global__ __launch_bounds__(512) void precompute_kernel(
    const float* __restrict__ mu, const float* __restrict__ Coo_inv,
    const int* __restrict__ obs_ix, const float* __restrict__ log_prop,
    float* __restrict__ w_buf, float* __restrict__ b_buf,
    int* __restrict__ gcount)
{
    __shared__ float cinv[DD * DD];      // 14.4 KB
    __shared__ float nu_lds[128 * 61];   // 31.2 KB (stride 61: conflict-free)
    __shared__ float q2_lds[128 * 4];

    const int b   = blockIdx.x;
    const int h   = b >> 1;
    const int ub  = (b & 1) * 128;
    const int tid = threadIdx.x;

    if (tid < 32) gcount[b * 32 + tid] = 0;   // 256 blocks x 32 = all counters

    // stage Cinv[h]: 900 float4, coalesced (3600*4B row offset is 16B-aligned)
    {
        const float4* __restrict__ src = (const float4*)(Coo_inv + h * DD * DD);
        float4* __restrict__ dst = (float4*)cinv;
        for (int i = tid; i < (DD * DD) / 4; i += 512) dst[i] = src[i];
    }

    // gather nu for 128 units into LDS (15 dims per thread)
    {
        const int ut  = tid >> 2;
        const int dqt = tid & 3;
        const float* __restrict__ mub = mu + (ub + ut) * (RANK * NC);
#pragma unroll
        for (int j = 0; j < DD4; ++j) {
            const int d  = dqt * DD4 + j;
            const int r  = d / NC_OBS;
            const int jj = d - r * NC_OBS;
            const int ch = obs_ix[h * NC_OBS + jj];
            nu_lds[ut * 61 + d] = mub[r * NC + ch];
        }
    }
    __syncthreads();

    const int lane  = tid & 63;
    const int wave  = tid >> 6;
    const int ug    = wave >> 2;
    const int dq    = __builtin_amdgcn_readfirstlane(wave & 3);
    const int u_loc = ug * 64 + lane;
    const int u     = ub + u_loc;
    const int p     = h * N_UNITS + u;

    float wreg[DD4];
#pragma unroll
    for (int j = 0; j < DD4; ++j) wreg[j] = 0.f;

    const float* __restrict__ Crow_base = cinv + dq * DD4;
    for (int e = 0; e < DD; ++e) {
        const float nu_e = nu_lds[u_loc * 61 + e];          // per-lane ds_read
        const float* __restrict__ Crow = Crow_base + e * DD; // LDS, wave-uniform
#pragma unroll
        for (int j = 0; j < DD4; ++j)
            wreg[j] = fmaf(Crow[j], nu_e, wreg[j]);
    }

    float q2 = 0.f;
#pragma unroll
    for (int j = 0; j < DD4; ++j) q2 += wreg[j] * nu_lds[u_loc * 61 + dq * DD4 + j];
    q2_lds[u_loc * 4 + dq] = q2;

    float* __restrict__ wp = w_buf + p * DD + dq * DD4;
#pragma unroll
    for (int j = 0; j < DD4; ++j) wp[j] = wreg[j];

    __syncthreads();
    if ((wave & 3) == 0) {
        const float q2s = q2_lds[u_loc * 4 + 0] + q2_lds[u_loc * 4 + 1]
                        + q2_lds[u_loc * 4 + 2] + q2_lds[u_loc * 4 + 3];
        b_buf[p] = log_prop[u] - 0.5f * q2s;
    }
}

// ---------------------------------------------------------------------------
// Kernel S1: q-compute + bin (candidate-per-lane core).  Unchanged from R5.
// ---------------------------------------------------------------------------
__global__ __launch_bounds__(1024) void spike_bin_kernel(
    const float* __restrict__ features, const float* __restrict__ noise_lp,
    const int* __restrict__ cands, const int* __restrict__ nid,
    const float* __restrict__ w_buf, const float* __restrict__ b_buf,
    int* __restrict__ gcount, int2* __restrict__ bins)
{
    const int tid  = threadIdx.x;
    const int lane = tid & 63;
    const int wave = tid >> 6;          // 0..15
    const int c    = lane & 15;         // candidate slot (0..9 active)
    const int s    = lane >> 4;         // spike slot within wave
    const int n    = blockIdx.x * 64 + wave * 4 + s;
    const int sb   = blockIdx.x & (NSB - 1);
    const bool act = (c < N_CAND);
    const int cc   = act ? c : (N_CAND - 1);

    const float4* __restrict__ f4 = (const float4*)features;
    const float4* __restrict__ w4 = (const float4*)w_buf;

    const int   h   = nid[n];
    const float nlp = noise_lp[0];
    const int   uc  = cands[n * N_CAND + cc];
    const int   p   = h * N_UNITS + uc;
    const float bb  = b_buf[p];

    float t = 0.f;
#pragma unroll
    for (int k = 0; k < DD4; ++k) {
        const float4 wv = w4[p * DD4 + k];
        const float4 xv = f4[n * DD4 + k];   // same addr across group: L1 bcast
        t += wv.x * xv.x + wv.y * xv.y + wv.z * xv.z + wv.w * xv.w;
    }
    float ll = act ? (bb + t) : -3.4e38f;

    float m = ll;
    m = fmaxf(m, __shfl_xor(m, 1, 16));
    m = fmaxf(m, __shfl_xor(m, 2, 16));
    m = fmaxf(m, __shfl_xor(m, 4, 16));
    m = fmaxf(m, __shfl_xor(m, 8, 16));
    m = fmaxf(m, nlp);
    const float e = act ? __expf(ll - m) : 0.f;
    float ssum = e;
    ssum += __shfl_xor(ssum, 1, 16);
    ssum += __shfl_xor(ssum, 2, 16);
    ssum += __shfl_xor(ssum, 4, 16);
    ssum += __shfl_xor(ssum, 8, 16);
    ssum += __expf(nlp - m);
    const float q = e / ssum;

    if (act && q > 0.f) {
        const int bi  = uc * NSB + sb;
        const int pos = atomicAdd(&gcount[bi * CNT_PAD], 1);
        if (pos < SCAP) bins[bi * SCAP + pos] = make_int2(n, __float_as_int(q));
    }
}

// ---------------------------------------------------------------------------
// Kernel S2: per-unit gather-accumulate.  Unchanged from R5 except rec[]
// sized to NSB*SCAP = 1536 (fixes latent overflow when sub-bin counts sum
// past 1024; the wave-parallel staging already handles arbitrary offsets).
// ---------------------------------------------------------------------------
__global__ __launch_bounds__(512) void unit_accum_kernel(
    const float* __restrict__ features, const int* __restrict__ gcount,
    const int2* __restrict__ bins, float* __restrict__ out)
{
    __shared__ int2  rec[CAP];          // 12 KB
    __shared__ float red[8][OUT_COLS];
    __shared__ int   cnts[NSB];
    __shared__ int   offs[NSB + 1];

    const int u    = blockIdx.x;
    const int tid  = threadIdx.x;
    const int lane = tid & 63;
    const int wave = tid >> 6;          // 0..7 == sub-bin it stages

    if (tid < NSB) {
        int c = gcount[(u * NSB + tid) * CNT_PAD];
        cnts[tid] = c < SCAP ? c : SCAP;
    }
    __syncthreads();
    if (tid == 0) {
        int o = 0;
#pragma unroll
        for (int sb = 0; sb < NSB; ++sb) { offs[sb] = o; o += cnts[sb]; }
        offs[NSB] = o;
    }
    __syncthreads();

    {   // wave-parallel staging: wave w copies sub-bin w
        const int base = offs[wave];
        const int cnt  = cnts[wave];
        const int2* __restrict__ src = bins + (u * NSB + wave) * SCAP;
        for (int i = lane; i < cnt; i += 64) rec[base + i] = src[i];
    }
    __syncthreads();

    const int total = offs[NSB];
    const int g = tid >> 4;             // group 0..31
    const int l = lane & 15;

    const float4* __restrict__ f4 = (const float4*)features;
    float4 a = {0.f, 0.f, 0.f, 0.f};
    float sq = 0.f;

    for (int i = g; i < total; i += 32) {
        const int2 r = rec[i];                   // LDS broadcast within group
        const float q = __int_as_float(r.y);
        if (l < DD4) {
            const float4 xv = f4[r.x * DD4 + l]; // 15 lanes: 240B contiguous
            a.x = fmaf(q, xv.x, a.x);
            a.y = fmaf(q, xv.y, a.y);
            a.z = fmaf(q, xv.z, a.z);
            a.w = fmaf(q, xv.w, a.w);
        } else if (l == DD4) {
            sq += q;
        }
    }

    // reduce across the 4 groups within each wave
    a.x += __shfl_xor(a.x, 16, 64);  a.x += __shfl_xor(a.x, 32, 64);
    a.y += __shfl_xor(a.y, 16, 64);  a.y += __shfl_xor(a.y, 32, 64);
    a.z += __shfl_xor(a.z, 16, 64);  a.z += __shfl_xor(a.z, 32, 64);
    a.w += __shfl_xor(a.w, 16, 64);  a.w += __shfl_xor(a.w, 32, 64);
    sq  += __shfl_xor(sq, 16, 64);   sq  += __shfl_xor(sq, 32, 64);

    if (lane < DD4) {                 // group 0 of each wave writes the partial
        red[wave][1 + 4*lane + 0] = a.x;
        red[wave][1 + 4*lane + 1] = a.y;
        red[wave][1 + 4*lane + 2] = a.z;
        red[wave][1 + 4*lane + 3] = a.w;
    } else if (lane == DD4) {
        red[wave][0] = sq;
    }
    __syncthreads();

    if (tid < OUT_COLS) {
        float ssum = 0.f;
#pragma unroll
        for (int w = 0; w < 8; ++w) ssum += red[w][tid];
        out[u * OUT_COLS + tid] = ssum;
    }
}

extern "C" void kernel_launch(void* const* d_in, const int* in_sizes, int n_in,
                              void* d_out, int out_size, void* d_ws, size_t ws_size,
                              hipStream_t stream) {
    const float* features    = (const float*)d_in[0];
    const float* mu          = (const float*)d_in[1];
    const float* Coo_inv     = (const float*)d_in[2];
    // d_in[3] = Coo_logdet : unused (cancels in softmax)
    const float* log_prop    = (const float*)d_in[4];
    const float* noise_lp    = (const float*)d_in[5];
    const int*   cands       = (const int*)d_in[6];
    const int*   nid         = (const int*)d_in[7];
    const int*   obs_ix      = (const int*)d_in[8];
    float* out = (float*)d_out;

    char* ws = (char*)d_ws;
    float* w_buf  = (float*)ws;                   // 128*256*60*4 = 7,864,320 B
    float* b_buf  = (float*)(ws + 7864320);       // 128*256*4    =   131,072 B
    int*   gcount = (int*)(ws + 7995392);         // 256*8*4*4    =    32,768 B
    int2*  bins   = (int2*)(ws + 8028160);        // 256*8*192*8  = 3,145,728 B
                                                  // total          11,173,888 B

    precompute_kernel<<<256, 512, 0, stream>>>(mu, Coo_inv, obs_ix, log_prop,
                                               w_buf, b_buf, gcount);
    spike_bin_kernel<<<256, 1024, 0, stream>>>(features, noise_lp, cands, nid,
                                               w_buf, b_buf, gcount, bins);
    unit_accum_kernel<<<256, 512, 0, stream>>>(features, gcount, bins, out);
}

// Round 8
// 110.091 us; speedup vs baseline: 3.5798x; 1.0085x over previous
//
#include <hip/hip_runtime.h>

#define N_SPIKES 16384
#define N_UNITS  256
#define N_NEIGHB 128
#define RANK     5
#define NC       64
#define NC_OBS   12
#define N_CAND   10
#define DD       60                 // RANK * NC_OBS
#define DD4      15                 // DD / 4
#define OUT_COLS 61
#define OUT_SIZE (N_UNITS * OUT_COLS)   // 15616
#define NSB      8                  // sub-bins per unit (counter de-contention)
#define SCAP     192                // per-sub-bin capacity (mean 80, sd 8.9)
#define CNT_PAD  4                  // 16B per counter
#define CAP      (NSB * SCAP)       // 1536: S2 staging holds worst case
#define CPAD     64                 // Cinv staged row stride (16B-aligned slices)

// ---------------------------------------------------------------------------
// Kernel P v4: aligned-vector Cinv reads.  R7 post-mortem: v3's inner loop
// still issued 16 scalar ds_read_b32 per e (the dq*15-float slice is 60B
// offset -> never 16B aligned -> no b128), ~7.7K LDS instrs/CU ~= 18us,
// same magnitude as v2's s_load chain (hence the neutral -1.4).  v4 stages
// Cinv padded to [60][64] (15.4KB) and assigns each wave a 16-COLUMN slice:
// per e = 4x ds_read_b128 at e*256 + dq*64 bytes (aligned, wave-uniform
// broadcast) + 1 per-lane nu read.  LDS instrs per e: 16 -> 5.
// Grid 512 x 256thr (4 waves = 4 dq, 64 units/block) -> 2 blocks/CU.
// Pad cols 60..63 staged as 0; q2/store mask them.  Zeroes gcount.
// ---------------------------------------------------------------------------
__global__ __launch_bounds__(256) void precompute_kernel(
    const float* __restrict__ mu, const float* __restrict__ Coo_inv,
    const int* __restrict__ obs_ix, const float* __restrict__ log_prop,
    float* __restrict__ w_buf, float* __restrict__ b_buf,
    int* __restrict__ gcount)
{
    __shared__ float cinv[DD * CPAD];    // 15.4 KB, row stride 64 floats
    __shared__ float nu_lds[64 * 61];    // 15.6 KB (stride 61: conflict-free)
    __shared__ float q2_lds[64 * 4];

    const int b   = blockIdx.x;
    const int h   = b >> 2;
    const int ub  = (b & 3) * 64;        // this block's 64 units
    const int tid = threadIdx.x;

    if (tid < 16) gcount[b * 16 + tid] = 0;   // 512 blocks x 16 = all 8192

    // stage Cinv[h] padded: cinv[e][c] = c<60 ? C[e*60+c] : 0
    {
        const float* __restrict__ src = Coo_inv + h * DD * DD;
        for (int idx = tid; idx < DD * CPAD; idx += 256) {
            const int e = idx >> 6;
            const int c = idx & 63;
            cinv[idx] = (c < DD) ? src[e * DD + c] : 0.f;
        }
    }

    // gather nu for 64 units into LDS (15 dims per thread, 4 threads/unit)
    {
        const int ut  = tid >> 2;        // unit 0..63
        const int dqt = tid & 3;
        const float* __restrict__ mub = mu + (ub + ut) * (RANK * NC);
#pragma unroll
        for (int j = 0; j < DD4; ++j) {
            const int d  = dqt * DD4 + j;
            const int r  = d / NC_OBS;
            const int jj = d - r * NC_OBS;
            const int ch = obs_ix[h * NC_OBS + jj];   // wave-uniform
            nu_lds[ut * 61 + d] = mub[r * NC + ch];
        }
    }
    __syncthreads();

    const int lane = tid & 63;           // unit within block
    const int dq   = __builtin_amdgcn_readfirstlane(tid >> 6);  // col slice 0..3
    const int u    = ub + lane;
    const int p    = h * N_UNITS + u;

    float wreg[16];
#pragma unroll
    for (int j = 0; j < 16; ++j) wreg[j] = 0.f;

    const float* __restrict__ Cslice = cinv + dq * 16;
#pragma unroll 4
    for (int e = 0; e < DD; ++e) {
        const float nu_e = nu_lds[lane * 61 + e];          // per-lane ds_read
        const float4* __restrict__ c4 =
            (const float4*)(Cslice + e * CPAD);            // aligned, broadcast
        const float4 c0 = c4[0], c1 = c4[1], c2 = c4[2], c3 = c4[3];
        wreg[ 0] = fmaf(c0.x, nu_e, wreg[ 0]);
        wreg[ 1] = fmaf(c0.y, nu_e, wreg[ 1]);
        wreg[ 2] = fmaf(c0.z, nu_e, wreg[ 2]);
        wreg[ 3] = fmaf(c0.w, nu_e, wreg[ 3]);
        wreg[ 4] = fmaf(c1.x, nu_e, wreg[ 4]);
        wreg[ 5] = fmaf(c1.y, nu_e, wreg[ 5]);
        wreg[ 6] = fmaf(c1.z, nu_e, wreg[ 6]);
        wreg[ 7] = fmaf(c1.w, nu_e, wreg[ 7]);
        wreg[ 8] = fmaf(c2.x, nu_e, wreg[ 8]);
        wreg[ 9] = fmaf(c2.y, nu_e, wreg[ 9]);
        wreg[10] = fmaf(c2.z, nu_e, wreg[10]);
        wreg[11] = fmaf(c2.w, nu_e, wreg[11]);
        wreg[12] = fmaf(c3.x, nu_e, wreg[12]);
        wreg[13] = fmaf(c3.y, nu_e, wreg[13]);
        wreg[14] = fmaf(c3.z, nu_e, wreg[14]);
        wreg[15] = fmaf(c3.w, nu_e, wreg[15]);
    }

    // q2 partial over this wave's columns (mask pad cols: wreg is 0 there,
    // but nu_lds slot 60 is uninitialized -> guard the product, not just w)
    float q2 = 0.f;
#pragma unroll
    for (int j = 0; j < 16; ++j) {
        const int c = dq * 16 + j;
        const float nv = nu_lds[lane * 61 + (c < DD ? c : 0)];
        q2 += (c < DD) ? wreg[j] * nv : 0.f;
    }
    q2_lds[lane * 4 + dq] = q2;

    // store this wave's 16-col slice of w (skip pad cols at dq==3)
    {
        float* __restrict__ wp = w_buf + p * DD + dq * 16;
#pragma unroll
        for (int k = 0; k < 4; ++k) {
            if (dq * 16 + k * 4 < DD) {
                float4 o;
                o.x = wreg[4*k+0]; o.y = wreg[4*k+1];
                o.z = wreg[4*k+2]; o.w = wreg[4*k+3];
                *(float4*)(wp + k * 4) = o;
            }
        }
    }

    __syncthreads();
    if (dq == 0) {   // wave 0: one lane per unit finalizes b
        const float q2s = q2_lds[lane * 4 + 0] + q2_lds[lane * 4 + 1]
                        + q2_lds[lane * 4 + 2] + q2_lds[lane * 4 + 3];
        b_buf[p] = log_prop[u] - 0.5f * q2s;
    }
}

// ---------------------------------------------------------------------------
// Kernel S1: q-compute + bin (candidate-per-lane core).  Unchanged from R5
// except gcount zeroing now covers 512*16 (see P).
// ---------------------------------------------------------------------------
__global__ __launch_bounds__(1024) void spike_bin_kernel(
    const float* __restrict__ features, const float* __restrict__ noise_lp,
    const int* __restrict__ cands, const int* __restrict__ nid,
    const float* __restrict__ w_buf, const float* __restrict__ b_buf,
    int* __restrict__ gcount, int2* __restrict__ bins)
{
    const int tid  = threadIdx.x;
    const int lane = tid & 63;
    const int wave = tid >> 6;          // 0..15
    const int c    = lane & 15;         // candidate slot (0..9 active)
    const int s    = lane >> 4;         // spike slot within wave
    const int n    = blockIdx.x * 64 + wave * 4 + s;
    const int sb   = blockIdx.x & (NSB - 1);
    const bool act = (c < N_CAND);
    const int cc   = act ? c : (N_CAND - 1);

    const float4* __restrict__ f4 = (const float4*)features;
    const float4* __restrict__ w4 = (const float4*)w_buf;

    const int   h   = nid[n];
    const float nlp = noise_lp[0];
    const int   uc  = cands[n * N_CAND + cc];
    const int   p   = h * N_UNITS + uc;
    const float bb  = b_buf[p];

    float t = 0.f;
#pragma unroll
    for (int k = 0; k < DD4; ++k) {
        const float4 wv = w4[p * DD4 + k];
        const float4 xv = f4[n * DD4 + k];   // same addr across group: L1 bcast
        t += wv.x * xv.x + wv.y * xv.y + wv.z * xv.z + wv.w * xv.w;
    }
    float ll = act ? (bb + t) : -3.4e38f;

    float m = ll;
    m = fmaxf(m, __shfl_xor(m, 1, 16));
    m = fmaxf(m, __shfl_xor(m, 2, 16));
    m = fmaxf(m, __shfl_xor(m, 4, 16));
    m = fmaxf(m, __shfl_xor(m, 8, 16));
    m = fmaxf(m, nlp);
    const float e = act ? __expf(ll - m) : 0.f;
    float ssum = e;
    ssum += __shfl_xor(ssum, 1, 16);
    ssum += __shfl_xor(ssum, 2, 16);
    ssum += __shfl_xor(ssum, 4, 16);
    ssum += __shfl_xor(ssum, 8, 16);
    ssum += __expf(nlp - m);
    const float q = e / ssum;

    if (act && q > 0.f) {
        const int bi  = uc * NSB + sb;
        const int pos = atomicAdd(&gcount[bi * CNT_PAD], 1);
        if (pos < SCAP) bins[bi * SCAP + pos] = make_int2(n, __float_as_int(q));
    }
}

// ---------------------------------------------------------------------------
// Kernel S2: per-unit gather-accumulate.  Unchanged from R7.
// ---------------------------------------------------------------------------
__global__ __launch_bounds__(512) void unit_accum_kernel(
    const float* __restrict__ features, const int* __restrict__ gcount,
    const int2* __restrict__ bins, float* __restrict__ out)
{
    __shared__ int2  rec[CAP];          // 12 KB
    __shared__ float red[8][OUT_COLS];
    __shared__ int   cnts[NSB];
    __shared__ int   offs[NSB + 1];

    const int u    = blockIdx.x;
    const int tid  = threadIdx.x;
    const int lane = tid & 63;
    const int wave = tid >> 6;          // 0..7 == sub-bin it stages

    if (tid < NSB) {
        int c = gcount[(u * NSB + tid) * CNT_PAD];
        cnts[tid] = c < SCAP ? c : SCAP;
    }
    __syncthreads();
    if (tid == 0) {
        int o = 0;
#pragma unroll
        for (int sb = 0; sb < NSB; ++sb) { offs[sb] = o; o += cnts[sb]; }
        offs[NSB] = o;
    }
    __syncthreads();

    {   // wave-parallel staging: wave w copies sub-bin w
        const int base = offs[wave];
        const int cnt  = cnts[wave];
        const int2* __restrict__ src = bins + (u * NSB + wave) * SCAP;
        for (int i = lane; i < cnt; i += 64) rec[base + i] = src[i];
    }
    __syncthreads();

    const int total = offs[NSB];
    const int g = tid >> 4;             // group 0..31
    const int l = lane & 15;

    const float4* __restrict__ f4 = (const float4*)features;
    float4 a = {0.f, 0.f, 0.f, 0.f};
    float sq = 0.f;

    for (int i = g; i < total; i += 32) {
        const int2 r = rec[i];                   // LDS broadcast within group
        const float q = __int_as_float(r.y);
        if (l < DD4) {
            const float4 xv = f4[r.x * DD4 + l]; // 15 lanes: 240B contiguous
            a.x = fmaf(q, xv.x, a.x);
            a.y = fmaf(q, xv.y, a.y);
            a.z = fmaf(q, xv.z, a.z);
            a.w = fmaf(q, xv.w, a.w);
        } else if (l == DD4) {
            sq += q;
        }
    }

    // reduce across the 4 groups within each wave
    a.x += __shfl_xor(a.x, 16, 64);  a.x += __shfl_xor(a.x, 32, 64);
    a.y += __shfl_xor(a.y, 16, 64);  a.y += __shfl_xor(a.y, 32, 64);
    a.z += __shfl_xor(a.z, 16, 64);  a.z += __shfl_xor(a.z, 32, 64);
    a.w += __shfl_xor(a.w, 16, 64);  a.w += __shfl_xor(a.w, 32, 64);
    sq  += __shfl_xor(sq, 16, 64);   sq  += __shfl_xor(sq, 32, 64);

    if (lane < DD4) {                 // group 0 of each wave writes the partial
        red[wave][1 + 4*lane + 0] = a.x;
        red[wave][1 + 4*lane + 1] = a.y;
        red[wave][1 + 4*lane + 2] = a.z;
        red[wave][1 + 4*lane + 3] = a.w;
    } else if (lane == DD4) {
        red[wave][0] = sq;
    }
    __syncthreads();

    if (tid < OUT_COLS) {
        float ssum = 0.f;
#pragma unroll
        for (int w = 0; w < 8; ++w) ssum += red[w][tid];
        out[u * OUT_COLS + tid] = ssum;
    }
}

extern "C" void kernel_launch(void* const* d_in, const int* in_sizes, int n_in,
                              void* d_out, int out_size, void* d_ws, size_t ws_size,
                              hipStream_t stream) {
    const float* features    = (const float*)d_in[0];
    const float* mu          = (const float*)d_in[1];
    const float* Coo_inv     = (const float*)d_in[2];
    // d_in[3] = Coo_logdet : unused (cancels in softmax)
    const float* log_prop    = (const float*)d_in[4];
    const float* noise_lp    = (const float*)d_in[5];
    const int*   cands       = (const int*)d_in[6];
    const int*   nid         = (const int*)d_in[7];
    const int*   obs_ix      = (const int*)d_in[8];
    float* out = (float*)d_out;

    char* ws = (char*)d_ws;
    float* w_buf  = (float*)ws;                   // 128*256*60*4 = 7,864,320 B
    float* b_buf  = (float*)(ws + 7864320);       // 128*256*4    =   131,072 B
    int*   gcount = (int*)(ws + 7995392);         // 256*8*4*4    =    32,768 B
    int2*  bins   = (int2*)(ws + 8028160);        // 256*8*192*8  = 3,145,728 B
                                                  // total          11,173,888 B

    precompute_kernel<<<512, 256, 0, stream>>>(mu, Coo_inv, obs_ix, log_prop,
                                               w_buf, b_buf, gcount);
    spike_bin_kernel<<<256, 1024, 0, stream>>>(features, noise_lp, cands, nid,
                                               w_buf, b_buf, gcount, bins);
    unit_accum_kernel<<<256, 512, 0, stream>>>(features, gcount, bins, out);
}

// Round 9
// 105.607 us; speedup vs baseline: 3.7318x; 1.0425x over previous
//
#include <hip/hip_runtime.h>

#define N_SPIKES 16384
#define N_UNITS  256
#define N_NEIGHB 128
#define RANK     5
#define NC       64
#define NC_OBS   12
#define N_CAND   10
#define DD       60                 // RANK * NC_OBS
#define DD4      15                 // DD / 4
#define WROW4    16                 // padded w row: 15 float4 of w + {b,0,0,0}
#define OUT_COLS 61
#define OUT_SIZE (N_UNITS * OUT_COLS)   // 15616
#define NSB      8                  // sub-bins per unit (counter de-contention)
#define SCAP     192                // per-sub-bin capacity (mean 80, sd 8.9)
#define CNT_PAD  4                  // 16B per counter
#define CAP      (NSB * SCAP)       // 1536: S2 staging holds worst case
#define CPAD     64                 // Cinv staged row stride (16B-aligned slices)

// ---------------------------------------------------------------------------
// Kernel P v4b: unchanged aligned-LDS structure (three P variants measured
// neutral => P ~= 11us, not the bottleneck; keep the best one).  Single
// change: w rows padded to 16 float4, slot 15 = {b, 0,0,0} so S1 reads b
// on the same cache lines as w (kills its separate scattered 4B load).
// ---------------------------------------------------------------------------
__global__ __launch_bounds__(256) void precompute_kernel(
    const float* __restrict__ mu, const float* __restrict__ Coo_inv,
    const int* __restrict__ obs_ix, const float* __restrict__ log_prop,
    float* __restrict__ w_buf, int* __restrict__ gcount)
{
    __shared__ float cinv[DD * CPAD];    // 15.4 KB, row stride 64 floats
    __shared__ float nu_lds[64 * 61];    // 15.6 KB (stride 61: conflict-free)
    __shared__ float q2_lds[64 * 4];

    const int b   = blockIdx.x;
    const int h   = b >> 2;
    const int ub  = (b & 3) * 64;        // this block's 64 units
    const int tid = threadIdx.x;

    if (tid < 16) gcount[b * 16 + tid] = 0;   // 512 blocks x 16 = all 8192

    // stage Cinv[h] padded: cinv[e][c] = c<60 ? C[e*60+c] : 0
    {
        const float* __restrict__ src = Coo_inv + h * DD * DD;
        for (int idx = tid; idx < DD * CPAD; idx += 256) {
            const int e = idx >> 6;
            const int c = idx & 63;
            cinv[idx] = (c < DD) ? src[e * DD + c] : 0.f;
        }
    }

    // gather nu for 64 units into LDS (15 dims per thread, 4 threads/unit)
    {
        const int ut  = tid >> 2;        // unit 0..63
        const int dqt = tid & 3;
        const float* __restrict__ mub = mu + (ub + ut) * (RANK * NC);
#pragma unroll
        for (int j = 0; j < DD4; ++j) {
            const int d  = dqt * DD4 + j;
            const int r  = d / NC_OBS;
            const int jj = d - r * NC_OBS;
            const int ch = obs_ix[h * NC_OBS + jj];   // wave-uniform
            nu_lds[ut * 61 + d] = mub[r * NC + ch];
        }
    }
    __syncthreads();

    const int lane = tid & 63;           // unit within block
    const int dq   = __builtin_amdgcn_readfirstlane(tid >> 6);  // col slice 0..3
    const int u    = ub + lane;
    const int p    = h * N_UNITS + u;

    float wreg[16];
#pragma unroll
    for (int j = 0; j < 16; ++j) wreg[j] = 0.f;

    const float* __restrict__ Cslice = cinv + dq * 16;
#pragma unroll 4
    for (int e = 0; e < DD; ++e) {
        const float nu_e = nu_lds[lane * 61 + e];          // per-lane ds_read
        const float4* __restrict__ c4 =
            (const float4*)(Cslice + e * CPAD);            // aligned, broadcast
        const float4 c0 = c4[0], c1 = c4[1], c2 = c4[2], c3 = c4[3];
        wreg[ 0] = fmaf(c0.x, nu_e, wreg[ 0]);
        wreg[ 1] = fmaf(c0.y, nu_e, wreg[ 1]);
        wreg[ 2] = fmaf(c0.z, nu_e, wreg[ 2]);
        wreg[ 3] = fmaf(c0.w, nu_e, wreg[ 3]);
        wreg[ 4] = fmaf(c1.x, nu_e, wreg[ 4]);
        wreg[ 5] = fmaf(c1.y, nu_e, wreg[ 5]);
        wreg[ 6] = fmaf(c1.z, nu_e, wreg[ 6]);
        wreg[ 7] = fmaf(c1.w, nu_e, wreg[ 7]);
        wreg[ 8] = fmaf(c2.x, nu_e, wreg[ 8]);
        wreg[ 9] = fmaf(c2.y, nu_e, wreg[ 9]);
        wreg[10] = fmaf(c2.z, nu_e, wreg[10]);
        wreg[11] = fmaf(c2.w, nu_e, wreg[11]);
        wreg[12] = fmaf(c3.x, nu_e, wreg[12]);
        wreg[13] = fmaf(c3.y, nu_e, wreg[13]);
        wreg[14] = fmaf(c3.z, nu_e, wreg[14]);
        wreg[15] = fmaf(c3.w, nu_e, wreg[15]);
    }

    // q2 partial over this wave's columns (guard pad cols AND uninit nu slot)
    float q2 = 0.f;
#pragma unroll
    for (int j = 0; j < 16; ++j) {
        const int c = dq * 16 + j;
        const float nv = nu_lds[lane * 61 + (c < DD ? c : 0)];
        q2 += (c < DD) ? wreg[j] * nv : 0.f;
    }
    q2_lds[lane * 4 + dq] = q2;

    // store this wave's 16-col slice of w (skip pad cols at dq==3)
    {
        float* __restrict__ wp = w_buf + p * (WROW4 * 4) + dq * 16;
#pragma unroll
        for (int k = 0; k < 4; ++k) {
            if (dq * 16 + k * 4 < DD) {
                float4 o;
                o.x = wreg[4*k+0]; o.y = wreg[4*k+1];
                o.z = wreg[4*k+2]; o.w = wreg[4*k+3];
                *(float4*)(wp + k * 4) = o;
            }
        }
    }

    __syncthreads();
    if (dq == 0) {   // wave 0: one lane per unit writes the b-slot (row 15)
        const float q2s = q2_lds[lane * 4 + 0] + q2_lds[lane * 4 + 1]
                        + q2_lds[lane * 4 + 2] + q2_lds[lane * 4 + 3];
        float4 bv;
        bv.x = log_prop[u] - 0.5f * q2s; bv.y = 0.f; bv.z = 0.f; bv.w = 0.f;
        *(float4*)(w_buf + p * (WROW4 * 4) + DD) = bv;
    }
}

// ---------------------------------------------------------------------------
// Kernel S1 v3: MLP-unstarved.  R8 theory: at launch_bounds(1024) the
// compiler got 32 VGPR, so the 30 independent float4 loads serialize in
// batches of ~2-3 (load-use stalls x ~10).  v3: 512-thr blocks with
// launch_bounds(512,4) (<=128 VGPR, same 16 waves/CU), ALL 16 w-float4
// (incl. the folded-in b) + 15 x-float4 hoisted into registers before any
// arithmetic -> every load in flight at once.  Logic otherwise identical.
// ---------------------------------------------------------------------------
__global__ __launch_bounds__(512, 4) void spike_bin_kernel(
    const float* __restrict__ features, const float* __restrict__ noise_lp,
    const int* __restrict__ cands, const int* __restrict__ nid,
    const float* __restrict__ w_buf,
    int* __restrict__ gcount, int2* __restrict__ bins)
{
    const int tid  = threadIdx.x;
    const int lane = tid & 63;
    const int wave = tid >> 6;          // 0..7
    const int c    = lane & 15;         // candidate slot (0..9 active)
    const int s    = lane >> 4;         // spike slot within wave
    const int n    = blockIdx.x * 32 + wave * 4 + s;
    const int sb   = blockIdx.x & (NSB - 1);
    const bool act = (c < N_CAND);
    const int cc   = act ? c : (N_CAND - 1);

    const float4* __restrict__ f4 = (const float4*)features;
    const float4* __restrict__ w4 = (const float4*)w_buf;

    const int   h   = nid[n];
    const float nlp = noise_lp[0];
    const int   uc  = cands[n * N_CAND + cc];
    const int   p   = h * N_UNITS + uc;

    // hoist ALL loads: 16 w-float4 (row p, incl b in slot 15) + 15 x-float4
    float4 wv[WROW4];
#pragma unroll
    for (int k = 0; k < WROW4; ++k) wv[k] = w4[p * WROW4 + k];
    float4 xv[DD4];
#pragma unroll
    for (int k = 0; k < DD4; ++k) xv[k] = f4[n * DD4 + k];  // group-bcast, L1

    float t = 0.f;
#pragma unroll
    for (int k = 0; k < DD4; ++k)
        t += wv[k].x*xv[k].x + wv[k].y*xv[k].y + wv[k].z*xv[k].z + wv[k].w*xv[k].w;
    const float bb = wv[DD4].x;
    float ll = act ? (bb + t) : -3.4e38f;

    float m = ll;
    m = fmaxf(m, __shfl_xor(m, 1, 16));
    m = fmaxf(m, __shfl_xor(m, 2, 16));
    m = fmaxf(m, __shfl_xor(m, 4, 16));
    m = fmaxf(m, __shfl_xor(m, 8, 16));
    m = fmaxf(m, nlp);
    const float e = act ? __expf(ll - m) : 0.f;
    float ssum = e;
    ssum += __shfl_xor(ssum, 1, 16);
    ssum += __shfl_xor(ssum, 2, 16);
    ssum += __shfl_xor(ssum, 4, 16);
    ssum += __shfl_xor(ssum, 8, 16);
    ssum += __expf(nlp - m);
    const float q = e / ssum;

    if (act) {
        const int bi  = uc * NSB + sb;
        const int pos = atomicAdd(&gcount[bi * CNT_PAD], 1);
        if (pos < SCAP) bins[bi * SCAP + pos] = make_int2(n, __float_as_int(q));
    }
}

// ---------------------------------------------------------------------------
// Kernel S2 v3: record loop unrolled x4 with loads hoisted ahead of the FMA
// block (same MLP mechanism as S1); launch_bounds(512,4) for VGPR headroom.
// Tail handled by a masked final pass.  Reduce path unchanged.
// ---------------------------------------------------------------------------
__global__ __launch_bounds__(512, 4) void unit_accum_kernel(
    const float* __restrict__ features, const int* __restrict__ gcount,
    const int2* __restrict__ bins, float* __restrict__ out)
{
    __shared__ int2  rec[CAP];          // 12 KB
    __shared__ float red[8][OUT_COLS];
    __shared__ int   cnts[NSB];
    __shared__ int   offs[NSB + 1];

    const int u    = blockIdx.x;
    const int tid  = threadIdx.x;
    const int lane = tid & 63;
    const int wave = tid >> 6;          // 0..7 == sub-bin it stages

    if (tid < NSB) {
        int c = gcount[(u * NSB + tid) * CNT_PAD];
        cnts[tid] = c < SCAP ? c : SCAP;
    }
    __syncthreads();
    if (tid == 0) {
        int o = 0;
#pragma unroll
        for (int sb = 0; sb < NSB; ++sb) { offs[sb] = o; o += cnts[sb]; }
        offs[NSB] = o;
    }
    __syncthreads();

    {   // wave-parallel staging: wave w copies sub-bin w
        const int base = offs[wave];
        const int cnt  = cnts[wave];
        const int2* __restrict__ src = bins + (u * NSB + wave) * SCAP;
        for (int i = lane; i < cnt; i += 64) rec[base + i] = src[i];
    }
    __syncthreads();

    const int total = offs[NSB];
    const int g = tid >> 4;             // group 0..31
    const int l = lane & 15;
    const bool dl = (l < DD4);

    const float4* __restrict__ f4 = (const float4*)features;
    float4 a = {0.f, 0.f, 0.f, 0.f};
    float sq = 0.f;

    int i = g;
    for (; i + 96 < total; i += 128) {      // 4 records per pass per group
        const int2 r0 = rec[i];
        const int2 r1 = rec[i + 32];
        const int2 r2 = rec[i + 64];
        const int2 r3 = rec[i + 96];
        const int li = dl ? l : 0;
        const float4 x0 = f4[r0.x * DD4 + li];   // 4 independent loads in flight
        const float4 x1 = f4[r1.x * DD4 + li];
        const float4 x2 = f4[r2.x * DD4 + li];
        const float4 x3 = f4[r3.x * DD4 + li];
        const float q0 = __int_as_float(r0.y), q1 = __int_as_float(r1.y);
        const float q2 = __int_as_float(r2.y), q3 = __int_as_float(r3.y);
        if (dl) {
            a.x = fmaf(q0, x0.x, a.x); a.y = fmaf(q0, x0.y, a.y);
            a.z = fmaf(q0, x0.z, a.z); a.w = fmaf(q0, x0.w, a.w);
            a.x = fmaf(q1, x1.x, a.x); a.y = fmaf(q1, x1.y, a.y);
            a.z = fmaf(q1, x1.z, a.z); a.w = fmaf(q1, x1.w, a.w);
            a.x = fmaf(q2, x2.x, a.x); a.y = fmaf(q2, x2.y, a.y);
            a.z = fmaf(q2, x2.z, a.z); a.w = fmaf(q2, x2.w, a.w);
            a.x = fmaf(q3, x3.x, a.x); a.y = fmaf(q3, x3.y, a.y);
            a.z = fmaf(q3, x3.z, a.z); a.w = fmaf(q3, x3.w, a.w);
        } else if (l == DD4) {
            sq += q0 + q1 + q2 + q3;
        }
    }
    for (; i < total; i += 32) {            // tail
        const int2 r = rec[i];
        const float q = __int_as_float(r.y);
        if (dl) {
            const float4 xv = f4[r.x * DD4 + l];
            a.x = fmaf(q, xv.x, a.x);
            a.y = fmaf(q, xv.y, a.y);
            a.z = fmaf(q, xv.z, a.z);
            a.w = fmaf(q, xv.w, a.w);
        } else if (l == DD4) {
            sq += q;
        }
    }

    // reduce across the 4 groups within each wave
    a.x += __shfl_xor(a.x, 16, 64);  a.x += __shfl_xor(a.x, 32, 64);
    a.y += __shfl_xor(a.y, 16, 64);  a.y += __shfl_xor(a.y, 32, 64);
    a.z += __shfl_xor(a.z, 16, 64);  a.z += __shfl_xor(a.z, 32, 64);
    a.w += __shfl_xor(a.w, 16, 64);  a.w += __shfl_xor(a.w, 32, 64);
    sq  += __shfl_xor(sq, 16, 64);   sq  += __shfl_xor(sq, 32, 64);

    if (lane < DD4) {                 // group 0 of each wave writes the partial
        red[wave][1 + 4*lane + 0] = a.x;
        red[wave][1 + 4*lane + 1] = a.y;
        red[wave][1 + 4*lane + 2] = a.z;
        red[wave][1 + 4*lane + 3] = a.w;
    } else if (lane == DD4) {
        red[wave][0] = sq;
    }
    __syncthreads();

    if (tid < OUT_COLS) {
        float ssum = 0.f;
#pragma unroll
        for (int w = 0; w < 8; ++w) ssum += red[w][tid];
        out[u * OUT_COLS + tid] = ssum;
    }
}

extern "C" void kernel_launch(void* const* d_in, const int* in_sizes, int n_in,
                              void* d_out, int out_size, void* d_ws, size_t ws_size,
                              hipStream_t stream) {
    const float* features    = (const float*)d_in[0];
    const float* mu          = (const float*)d_in[1];
    const float* Coo_inv     = (const float*)d_in[2];
    // d_in[3] = Coo_logdet : unused (cancels in softmax)
    const float* log_prop    = (const float*)d_in[4];
    const float* noise_lp    = (const float*)d_in[5];
    const int*   cands       = (const int*)d_in[6];
    const int*   nid         = (const int*)d_in[7];
    const int*   obs_ix      = (const int*)d_in[8];
    float* out = (float*)d_out;

    char* ws = (char*)d_ws;
    float* w_buf  = (float*)ws;                   // 128*256*64*4 = 8,388,608 B
    int*   gcount = (int*)(ws + 8388608);         // 512*16*4     =    32,768 B
    int2*  bins   = (int2*)(ws + 8421376);        // 256*8*192*8  = 3,145,728 B
                                                  // total          11,567,104 B

    precompute_kernel<<<512, 256, 0, stream>>>(mu, Coo_inv, obs_ix, log_prop,
                                               w_buf, gcount);
    spike_bin_kernel<<<512, 512, 0, stream>>>(features, noise_lp, cands, nid,
                                              w_buf, gcount, bins);
    unit_accum_kernel<<<256, 512, 0, stream>>>(features, gcount, bins, out);
}

// Round 10
// 105.540 us; speedup vs baseline: 3.7342x; 1.0006x over previous
//
#include <hip/hip_runtime.h>

#define N_SPIKES 16384
#define N_UNITS  256
#define N_NEIGHB 128
#define RANK     5
#define NC       64
#define NC_OBS   12
#define N_CAND   10
#define DD       60                 // RANK * NC_OBS
#define DD4      15                 // DD / 4
#define WROW4    16                 // padded w row: 15 float4 of w + {b,0,0,0}
#define OUT_COLS 61
#define OUT_SIZE (N_UNITS * OUT_COLS)   // 15616
#define NSB      8                  // sub-bins per unit (counter de-contention)
#define SCAP     192                // per-sub-bin capacity (mean 80, sd 8.9)
#define CNT_PAD  4                  // 16B per counter
#define CAP      (NSB * SCAP)       // 1536: S2 staging holds worst case
#define CPAD     64                 // Cinv staged row stride (16B-aligned slices)

// ---------------------------------------------------------------------------
// Kernel P v4b: UNCHANGED from R9 (two P-mechanism rewrites were neutral =>
// P ~= 10us, near its LDS-broadcast floor; frozen for attribution).
// ---------------------------------------------------------------------------
__global__ __launch_bounds__(256) void precompute_kernel(
    const float* __restrict__ mu, const float* __restrict__ Coo_inv,
    const int* __restrict__ obs_ix, const float* __restrict__ log_prop,
    float* __restrict__ w_buf, int* __restrict__ gcount)
{
    __shared__ float cinv[DD * CPAD];    // 15.4 KB, row stride 64 floats
    __shared__ float nu_lds[64 * 61];    // 15.6 KB (stride 61: conflict-free)
    __shared__ float q2_lds[64 * 4];

    const int b   = blockIdx.x;
    const int h   = b >> 2;
    const int ub  = (b & 3) * 64;        // this block's 64 units
    const int tid = threadIdx.x;

    if (tid < 16) gcount[b * 16 + tid] = 0;   // 512 blocks x 16 = all 8192

    {
        const float* __restrict__ src = Coo_inv + h * DD * DD;
        for (int idx = tid; idx < DD * CPAD; idx += 256) {
            const int e = idx >> 6;
            const int c = idx & 63;
            cinv[idx] = (c < DD) ? src[e * DD + c] : 0.f;
        }
    }

    {
        const int ut  = tid >> 2;        // unit 0..63
        const int dqt = tid & 3;
        const float* __restrict__ mub = mu + (ub + ut) * (RANK * NC);
#pragma unroll
        for (int j = 0; j < DD4; ++j) {
            const int d  = dqt * DD4 + j;
            const int r  = d / NC_OBS;
            const int jj = d - r * NC_OBS;
            const int ch = obs_ix[h * NC_OBS + jj];   // wave-uniform
            nu_lds[ut * 61 + d] = mub[r * NC + ch];
        }
    }
    __syncthreads();

    const int lane = tid & 63;           // unit within block
    const int dq   = __builtin_amdgcn_readfirstlane(tid >> 6);  // col slice 0..3
    const int u    = ub + lane;
    const int p    = h * N_UNITS + u;

    float wreg[16];
#pragma unroll
    for (int j = 0; j < 16; ++j) wreg[j] = 0.f;

    const float* __restrict__ Cslice = cinv + dq * 16;
#pragma unroll 4
    for (int e = 0; e < DD; ++e) {
        const float nu_e = nu_lds[lane * 61 + e];          // per-lane ds_read
        const float4* __restrict__ c4 =
            (const float4*)(Cslice + e * CPAD);            // aligned, broadcast
        const float4 c0 = c4[0], c1 = c4[1], c2 = c4[2], c3 = c4[3];
        wreg[ 0] = fmaf(c0.x, nu_e, wreg[ 0]);
        wreg[ 1] = fmaf(c0.y, nu_e, wreg[ 1]);
        wreg[ 2] = fmaf(c0.z, nu_e, wreg[ 2]);
        wreg[ 3] = fmaf(c0.w, nu_e, wreg[ 3]);
        wreg[ 4] = fmaf(c1.x, nu_e, wreg[ 4]);
        wreg[ 5] = fmaf(c1.y, nu_e, wreg[ 5]);
        wreg[ 6] = fmaf(c1.z, nu_e, wreg[ 6]);
        wreg[ 7] = fmaf(c1.w, nu_e, wreg[ 7]);
        wreg[ 8] = fmaf(c2.x, nu_e, wreg[ 8]);
        wreg[ 9] = fmaf(c2.y, nu_e, wreg[ 9]);
        wreg[10] = fmaf(c2.z, nu_e, wreg[10]);
        wreg[11] = fmaf(c2.w, nu_e, wreg[11]);
        wreg[12] = fmaf(c3.x, nu_e, wreg[12]);
        wreg[13] = fmaf(c3.y, nu_e, wreg[13]);
        wreg[14] = fmaf(c3.z, nu_e, wreg[14]);
        wreg[15] = fmaf(c3.w, nu_e, wreg[15]);
    }

    float q2 = 0.f;
#pragma unroll
    for (int j = 0; j < 16; ++j) {
        const int c = dq * 16 + j;
        const float nv = nu_lds[lane * 61 + (c < DD ? c : 0)];
        q2 += (c < DD) ? wreg[j] * nv : 0.f;
    }
    q2_lds[lane * 4 + dq] = q2;

    {
        float* __restrict__ wp = w_buf + p * (WROW4 * 4) + dq * 16;
#pragma unroll
        for (int k = 0; k < 4; ++k) {
            if (dq * 16 + k * 4 < DD) {
                float4 o;
                o.x = wreg[4*k+0]; o.y = wreg[4*k+1];
                o.z = wreg[4*k+2]; o.w = wreg[4*k+3];
                *(float4*)(wp + k * 4) = o;
            }
        }
    }

    __syncthreads();
    if (dq == 0) {   // wave 0: one lane per unit writes the b-slot (row 15)
        const float q2s = q2_lds[lane * 4 + 0] + q2_lds[lane * 4 + 1]
                        + q2_lds[lane * 4 + 2] + q2_lds[lane * 4 + 3];
        float4 bv;
        bv.x = log_prop[u] - 0.5f * q2s; bv.y = 0.f; bv.z = 0.f; bv.w = 0.f;
        *(float4*)(w_buf + p * (WROW4 * 4) + DD) = bv;
    }
}

// ---------------------------------------------------------------------------
// Kernel S1 v4: VGPR cap lifted.  R9's full 31-float4 hoist needs ~154 VGPR
// but launch_bounds(512,4) caps at 128 -> compiler re-serialized part of the
// batch (half-fixed R8 mechanism).  v4: (512,3) => ~170 VGPR budget, all 31
// loads genuinely in flight; 12 waves/CU (vs 16) is the price.  Logic
// identical to R9.
// ---------------------------------------------------------------------------
__global__ __launch_bounds__(512, 3) void spike_bin_kernel(
    const float* __restrict__ features, const float* __restrict__ noise_lp,
    const int* __restrict__ cands, const int* __restrict__ nid,
    const float* __restrict__ w_buf,
    int* __restrict__ gcount, int2* __restrict__ bins)
{
    const int tid  = threadIdx.x;
    const int lane = tid & 63;
    const int wave = tid >> 6;          // 0..7
    const int c    = lane & 15;         // candidate slot (0..9 active)
    const int s    = lane >> 4;         // spike slot within wave
    const int n    = blockIdx.x * 32 + wave * 4 + s;
    const int sb   = blockIdx.x & (NSB - 1);
    const bool act = (c < N_CAND);
    const int cc   = act ? c : (N_CAND - 1);

    const float4* __restrict__ f4 = (const float4*)features;
    const float4* __restrict__ w4 = (const float4*)w_buf;

    const int   h   = nid[n];
    const float nlp = noise_lp[0];
    const int   uc  = cands[n * N_CAND + cc];
    const int   p   = h * N_UNITS + uc;

    // hoist ALL loads: 16 w-float4 (row p, incl b in slot 15) + 15 x-float4
    float4 wv[WROW4];
#pragma unroll
    for (int k = 0; k < WROW4; ++k) wv[k] = w4[p * WROW4 + k];
    float4 xv[DD4];
#pragma unroll
    for (int k = 0; k < DD4; ++k) xv[k] = f4[n * DD4 + k];  // group-bcast

    float t = 0.f;
#pragma unroll
    for (int k = 0; k < DD4; ++k)
        t += wv[k].x*xv[k].x + wv[k].y*xv[k].y + wv[k].z*xv[k].z + wv[k].w*xv[k].w;
    const float bb = wv[DD4].x;
    float ll = act ? (bb + t) : -3.4e38f;

    float m = ll;
    m = fmaxf(m, __shfl_xor(m, 1, 16));
    m = fmaxf(m, __shfl_xor(m, 2, 16));
    m = fmaxf(m, __shfl_xor(m, 4, 16));
    m = fmaxf(m, __shfl_xor(m, 8, 16));
    m = fmaxf(m, nlp);
    const float e = act ? __expf(ll - m) : 0.f;
    float ssum = e;
    ssum += __shfl_xor(ssum, 1, 16);
    ssum += __shfl_xor(ssum, 2, 16);
    ssum += __shfl_xor(ssum, 4, 16);
    ssum += __shfl_xor(ssum, 8, 16);
    ssum += __expf(nlp - m);
    const float q = e / ssum;

    if (act) {
        const int bi  = uc * NSB + sb;
        const int pos = atomicAdd(&gcount[bi * CNT_PAD], 1);
        if (pos < SCAP) bins[bi * SCAP + pos] = make_int2(n, __float_as_int(q));
    }
}

// ---------------------------------------------------------------------------
// Kernel S2 v4: wave-doubled.  R9 ran 256 blocks x 512 thr = 1 block/CU,
// 8 waves/CU (2/SIMD) -- minimal TLP for the scattered feature gather.
// v4: 1024 thr (16 waves/CU), 64 record-groups, same unroll-4 loop.
// Staging still wave 0..7 (one sub-bin each); reduce over 16 wave partials.
// ---------------------------------------------------------------------------
__global__ __launch_bounds__(1024, 2) void unit_accum_kernel(
    const float* __restrict__ features, const int* __restrict__ gcount,
    const int2* __restrict__ bins, float* __restrict__ out)
{
    __shared__ int2  rec[CAP];          // 12 KB
    __shared__ float red[16][OUT_COLS]; // ~4 KB
    __shared__ int   cnts[NSB];
    __shared__ int   offs[NSB + 1];

    const int u    = blockIdx.x;
    const int tid  = threadIdx.x;
    const int lane = tid & 63;
    const int wave = tid >> 6;          // 0..15

    if (tid < NSB) {
        int c = gcount[(u * NSB + tid) * CNT_PAD];
        cnts[tid] = c < SCAP ? c : SCAP;
    }
    __syncthreads();
    if (tid == 0) {
        int o = 0;
#pragma unroll
        for (int sb = 0; sb < NSB; ++sb) { offs[sb] = o; o += cnts[sb]; }
        offs[NSB] = o;
    }
    __syncthreads();

    if (wave < NSB) {   // wave-parallel staging: wave w copies sub-bin w
        const int base = offs[wave];
        const int cnt  = cnts[wave];
        const int2* __restrict__ src = bins + (u * NSB + wave) * SCAP;
        for (int i = lane; i < cnt; i += 64) rec[base + i] = src[i];
    }
    __syncthreads();

    const int total = offs[NSB];
    const int g = tid >> 4;             // group 0..63
    const int l = lane & 15;
    const bool dl = (l < DD4);

    const float4* __restrict__ f4 = (const float4*)features;
    float4 a = {0.f, 0.f, 0.f, 0.f};
    float sq = 0.f;

    int i = g;
    for (; i + 192 < total; i += 256) {     // 4 records per pass per group
        const int2 r0 = rec[i];
        const int2 r1 = rec[i + 64];
        const int2 r2 = rec[i + 128];
        const int2 r3 = rec[i + 192];
        const int li = dl ? l : 0;
        const float4 x0 = f4[r0.x * DD4 + li];   // 4 independent loads in flight
        const float4 x1 = f4[r1.x * DD4 + li];
        const float4 x2 = f4[r2.x * DD4 + li];
        const float4 x3 = f4[r3.x * DD4 + li];
        const float q0 = __int_as_float(r0.y), q1 = __int_as_float(r1.y);
        const float q2 = __int_as_float(r2.y), q3 = __int_as_float(r3.y);
        if (dl) {
            a.x = fmaf(q0, x0.x, a.x); a.y = fmaf(q0, x0.y, a.y);
            a.z = fmaf(q0, x0.z, a.z); a.w = fmaf(q0, x0.w, a.w);
            a.x = fmaf(q1, x1.x, a.x); a.y = fmaf(q1, x1.y, a.y);
            a.z = fmaf(q1, x1.z, a.z); a.w = fmaf(q1, x1.w, a.w);
            a.x = fmaf(q2, x2.x, a.x); a.y = fmaf(q2, x2.y, a.y);
            a.z = fmaf(q2, x2.z, a.z); a.w = fmaf(q2, x2.w, a.w);
            a.x = fmaf(q3, x3.x, a.x); a.y = fmaf(q3, x3.y, a.y);
            a.z = fmaf(q3, x3.z, a.z); a.w = fmaf(q3, x3.w, a.w);
        } else if (l == DD4) {
            sq += q0 + q1 + q2 + q3;
        }
    }
    for (; i < total; i += 64) {            // tail
        const int2 r = rec[i];
        const float q = __int_as_float(r.y);
        if (dl) {
            const float4 xv = f4[r.x * DD4 + l];
            a.x = fmaf(q, xv.x, a.x);
            a.y = fmaf(q, xv.y, a.y);
            a.z = fmaf(q, xv.z, a.z);
            a.w = fmaf(q, xv.w, a.w);
        } else if (l == DD4) {
            sq += q;
        }
    }

    // reduce across the 4 groups within each wave
    a.x += __shfl_xor(a.x, 16, 64);  a.x += __shfl_xor(a.x, 32, 64);
    a.y += __shfl_xor(a.y, 16, 64);  a.y += __shfl_xor(a.y, 32, 64);
    a.z += __shfl_xor(a.z, 16, 64);  a.z += __shfl_xor(a.z, 32, 64);
    a.w += __shfl_xor(a.w, 16, 64);  a.w += __shfl_xor(a.w, 32, 64);
    sq  += __shfl_xor(sq, 16, 64);   sq  += __shfl_xor(sq, 32, 64);

    if (lane < DD4) {                 // group 0 of each wave writes the partial
        red[wave][1 + 4*lane + 0] = a.x;
        red[wave][1 + 4*lane + 1] = a.y;
        red[wave][1 + 4*lane + 2] = a.z;
        red[wave][1 + 4*lane + 3] = a.w;
    } else if (lane == DD4) {
        red[wave][0] = sq;
    }
    __syncthreads();

    if (tid < OUT_COLS) {
        float ssum = 0.f;
#pragma unroll
        for (int w = 0; w < 16; ++w) ssum += red[w][tid];
        out[u * OUT_COLS + tid] = ssum;
    }
}

extern "C" void kernel_launch(void* const* d_in, const int* in_sizes, int n_in,
                              void* d_out, int out_size, void* d_ws, size_t ws_size,
                              hipStream_t stream) {
    const float* features    = (const float*)d_in[0];
    const float* mu          = (const float*)d_in[1];
    const float* Coo_inv     = (const float*)d_in[2];
    // d_in[3] = Coo_logdet : unused (cancels in softmax)
    const float* log_prop    = (const float*)d_in[4];
    const float* noise_lp    = (const float*)d_in[5];
    const int*   cands       = (const int*)d_in[6];
    const int*   nid         = (const int*)d_in[7];
    const int*   obs_ix      = (const int*)d_in[8];
    float* out = (float*)d_out;

    char* ws = (char*)d_ws;
    float* w_buf  = (float*)ws;                   // 128*256*64*4 = 8,388,608 B
    int*   gcount = (int*)(ws + 8388608);         // 512*16*4     =    32,768 B
    int2*  bins   = (int2*)(ws + 8421376);        // 256*8*192*8  = 3,145,728 B
                                                  // total          11,567,104 B

    precompute_kernel<<<512, 256, 0, stream>>>(mu, Coo_inv, obs_ix, log_prop,
                                               w_buf, gcount);
    spike_bin_kernel<<<512, 512, 0, stream>>>(features, noise_lp, cands, nid,
                                              w_buf, gcount, bins);
    unit_accum_kernel<<<256, 1024, 0, stream>>>(features, gcount, bins, out);
}